// Round 12
// baseline (127.434 us; speedup 1.0000x reference)
//
#include <hip/hip_runtime.h>
#include <hip/hip_bf16.h>

#define B_ 128
#define L_ 196
#define D_ 1024

typedef __attribute__((ext_vector_type(8))) short short8v;
typedef __attribute__((ext_vector_type(4))) float f32x4;
typedef unsigned short ushort_t;

// d_ws layout (bytes). Total 59,277,312 (< proven 60.29 MB).
#define OFF_ATTBF   0UL          // 25088*1024*2 = 51,380,224
#define OFF_WBF     51380224UL   // 1024*1024*2  =  2,097,152 (ends 53,477,376)
#define OFF_SPART   53477376UL   // 16*25088*4   =  1,605,632 (ends 55,083,008)
#define OFF_CPART   55083008UL   // 8*128*1024*4 =  4,194,304 (ends 59,277,312)

__device__ inline unsigned short f2bf(float f) {
  unsigned int u = __float_as_uint(f);
  unsigned int r = (u + 0x7fffu + ((u >> 16) & 1u)) >> 16;
  return (unsigned short)r;
}

// ---------------- convert: att + Wa fp32 -> bf16 (16B stores; r5-proven) ----------------
__global__ void convert_kernel(const float* __restrict__ att, const float* __restrict__ Wa,
                               ushort_t* __restrict__ att_bf, ushort_t* __restrict__ W_bf) {
  const int n0 = (B_*L_*D_)/8;   // 3,211,264
  const int n1 = (D_*D_)/8;      //   131,072
  const int total = n0 + n1;
  for (int idx = blockIdx.x*blockDim.x + threadIdx.x; idx < total;
       idx += gridDim.x*blockDim.x) {
    const float4* s; ushort_t* d;
    if (idx < n0) { s = (const float4*)att + (size_t)idx*2; d = att_bf + (size_t)idx*8; }
    else { int i = idx - n0; s = (const float4*)Wa + (size_t)i*2; d = W_bf + (size_t)i*8; }
    float4 f0 = s[0], f1 = s[1];
    short8v o;
    o[0] = (short)f2bf(f0.x); o[1] = (short)f2bf(f0.y);
    o[2] = (short)f2bf(f0.z); o[3] = (short)f2bf(f0.w);
    o[4] = (short)f2bf(f1.x); o[5] = (short)f2bf(f1.y);
    o[6] = (short)f2bf(f1.z); o[7] = (short)f2bf(f1.w);
    *(short8v*)d = o;
  }
}

// ---------------- c-matrix GEMM: split-K x8, fp32-direct inputs (grid 64; r5-proven) ----------------
__device__ inline short8v ldfrag(const ushort_t* tile, int row, int c) {
  int phys = c ^ (row & 7);
  return *(const short8v*)(tile + row*64 + phys*8);
}

__global__ __launch_bounds__(256) void gemm_c_kernel(
    const float* __restrict__ x, const float* __restrict__ h,
    const float* __restrict__ Wi, const float* __restrict__ Wh,
    float* __restrict__ cpart) {
  __shared__ ushort_t lds[16384];   // A[128][64]@0, B[128][64]@8192 (bf16, swizzled)
  int bid = blockIdx.x;
  int e0 = (bid & 7)*128;
  int kc = bid >> 3;               // 0..7: K-chunk of 256 within the 2048 concat-K
  const float* Asrc = (kc < 4) ? x : h;
  const float* Bsrc = (kc < 4) ? Wi : Wh;
  int kb = (kc & 3)*256;
  int t = threadIdx.x, lane = t & 63, w = t >> 6;
  int wm = w >> 1, we = w & 1;
  int lrow = lane & 15, lk = lane >> 4;

  f32x4 acc[4][4];
  #pragma unroll
  for (int i = 0; i < 4; ++i)
    #pragma unroll
    for (int j = 0; j < 4; ++j) acc[i][j] = (f32x4){0.f, 0.f, 0.f, 0.f};

  for (int kt = 0; kt < 4; ++kt) {
    int k0 = kb + (kt << 6);
    #pragma unroll
    for (int q = 0; q < 4; ++q) {
      int li = t*4 + q;
      int r = li >> 3, c = li & 7;
      int phys = (c ^ (r & 7))*8;
      const float* sA = Asrc + r*1024 + k0 + c*8;
      float4 a0 = *(const float4*)sA, a1 = *(const float4*)(sA + 4);
      short8v oa;
      oa[0]=(short)f2bf(a0.x); oa[1]=(short)f2bf(a0.y); oa[2]=(short)f2bf(a0.z); oa[3]=(short)f2bf(a0.w);
      oa[4]=(short)f2bf(a1.x); oa[5]=(short)f2bf(a1.y); oa[6]=(short)f2bf(a1.z); oa[7]=(short)f2bf(a1.w);
      *(short8v*)(lds + r*64 + phys) = oa;
      const float* sB = Bsrc + (size_t)(e0 + r)*1024 + k0 + c*8;
      float4 b0 = *(const float4*)sB, b1 = *(const float4*)(sB + 4);
      short8v ob;
      ob[0]=(short)f2bf(b0.x); ob[1]=(short)f2bf(b0.y); ob[2]=(short)f2bf(b0.z); ob[3]=(short)f2bf(b0.w);
      ob[4]=(short)f2bf(b1.x); ob[5]=(short)f2bf(b1.y); ob[6]=(short)f2bf(b1.z); ob[7]=(short)f2bf(b1.w);
      *(short8v*)(lds + 8192 + r*64 + phys) = ob;
    }
    __syncthreads();
    #pragma unroll
    for (int hh = 0; hh < 2; ++hh) {
      short8v af[4], bfv[4];
      #pragma unroll
      for (int i = 0; i < 4; ++i) af[i]  = ldfrag(lds, wm*64 + i*16 + lrow, hh*4 + lk);
      #pragma unroll
      for (int j = 0; j < 4; ++j) bfv[j] = ldfrag(lds + 8192, we*64 + j*16 + lrow, hh*4 + lk);
      #pragma unroll
      for (int i = 0; i < 4; ++i)
        #pragma unroll
        for (int j = 0; j < 4; ++j)
          acc[i][j] = __builtin_amdgcn_mfma_f32_16x16x32_bf16(af[i], bfv[j], acc[i][j], 0, 0, 0);
    }
    __syncthreads();
  }

  float* outc = cpart + (size_t)kc*131072;
  #pragma unroll
  for (int i = 0; i < 4; ++i) {
    int m = wm*64 + i*16 + lk*4;
    #pragma unroll
    for (int j = 0; j < 4; ++j) {
      int e = e0 + we*64 + j*16 + lrow;
      #pragma unroll
      for (int r = 0; r < 4; ++r)
        outc[(m + r)*1024 + e] = acc[i][j][r];
    }
  }
}

// ---------------- 128x128 score GEMM: r7/r11-proven (single-buffer, 3 blocks/CU) ----------------
#define BARR()  __builtin_amdgcn_s_barrier()
#define VM0()   asm volatile("s_waitcnt vmcnt(0)" ::: "memory")

__device__ inline void stageS(const ushort_t* __restrict__ g, int k0, ushort_t* ldsbase, int t) {
  #pragma unroll
  for (int it = 0; it < 4; ++it) {
    int linear = it*4096 + t*16;
    int r = linear >> 7;
    int c = ((linear >> 4) & 7) ^ (r & 7);
    const ushort_t* src = g + (size_t)r*1024 + k0 + c*8;
    ushort_t* dst = ldsbase + ((it*4096 + ((t & 192) << 4)) >> 1);
    __builtin_amdgcn_global_load_lds((const __attribute__((address_space(1))) void*)src,
                                     (__attribute__((address_space(3))) void*)dst,
                                     16, 0, 0);
  }
}

__global__ __launch_bounds__(256) void gemm_score_kernel(
    const ushort_t* __restrict__ Amat, const ushort_t* __restrict__ Bmat,
    const float* __restrict__ cpart,
    const float* __restrict__ ba, const float* __restrict__ bh, const float* __restrict__ bi,
    const float* __restrict__ wd,
    float* __restrict__ spart) {
  __shared__ ushort_t lds[16384];   // 32 KB: A[128][64]@0, B[128][64]@8192 (elems)
  __shared__ float c_lds[256];
  int bid = blockIdx.x;
  int swz = (bid & 7)*196 + (bid >> 3);    // 1568 % 8 == 0 -> bijective XCD swizzle
  int m_blk = swz >> 3, n_blk = swz & 7;
  int m0 = m_blk*128, e0 = n_blk*128;
  int t = (int)threadIdx.x, lane = t & 63, w = t >> 6;
  int wm = w >> 1, we = w & 1;
  int lrow = lane & 15, lk = lane >> 4;

  // c_lds = biases + sum of 8 K-partials
  int bb0 = m0 / 196;
  {
    int bb = bb0 + (t >> 7);
    int e  = e0 + (t & 127);
    float v = ba[e] + bh[e] + bi[e];
    if (bb < 128) {
      #pragma unroll
      for (int p = 0; p < 8; ++p) v += cpart[p*131072 + bb*1024 + e];
    }
    c_lds[t] = v;
  }

  const ushort_t* aG = Amat + (size_t)m0*1024;
  const ushort_t* bG = Bmat + (size_t)e0*1024;

  int lrow7 = lrow & 7;
  const ushort_t* pA0 = lds + (wm*64 + lrow)*64 + ((lk)     ^ lrow7)*8;
  const ushort_t* pA1 = lds + (wm*64 + lrow)*64 + (((4+lk)) ^ lrow7)*8;
  const ushort_t* pB0 = lds + 8192 + (we*64 + lrow)*64 + ((lk)     ^ lrow7)*8;
  const ushort_t* pB1 = lds + 8192 + (we*64 + lrow)*64 + (((4+lk)) ^ lrow7)*8;

  f32x4 acc[4][4];
  #pragma unroll
  for (int i = 0; i < 4; ++i)
    #pragma unroll
    for (int j = 0; j < 4; ++j) acc[i][j] = (f32x4){0.f, 0.f, 0.f, 0.f};

  stageS(aG, 0, lds, t);
  stageS(bG, 0, lds + 8192, t);

  for (int kt = 0; kt < 16; ++kt) {
    VM0();
    BARR();
    __builtin_amdgcn_s_setprio(1);
    #pragma unroll
    for (int ks = 0; ks < 2; ++ks) {
      const ushort_t* pa = ks ? pA1 : pA0;
      const ushort_t* pb = ks ? pB1 : pB0;
      short8v af[4], bfv[4];
      #pragma unroll
      for (int i = 0; i < 4; ++i) af[i]  = *(const short8v*)(pa + i*1024);
      #pragma unroll
      for (int j = 0; j < 4; ++j) bfv[j] = *(const short8v*)(pb + j*1024);
      #pragma unroll
      for (int i = 0; i < 4; ++i)
        #pragma unroll
        for (int j = 0; j < 4; ++j)
          acc[i][j] = __builtin_amdgcn_mfma_f32_16x16x32_bf16(af[i], bfv[j], acc[i][j], 0, 0, 0);
    }
    __builtin_amdgcn_s_setprio(0);
    BARR();
    if (kt < 15) {
      stageS(aG, (kt+1)*64, lds, t);
      stageS(bG, (kt+1)*64, lds + 8192, t);
    }
  }

  int p = n_blk*2 + we;
  #pragma unroll
  for (int i = 0; i < 4; ++i) {
    int mbase = m0 + wm*64 + i*16 + lk*4;
    f32x4 ps;
    #pragma unroll
    for (int r = 0; r < 4; ++r) {
      int m = mbase + r;
      int bb = (int)((unsigned)m / 196u);
      float partial = 0.f;
      #pragma unroll
      for (int j = 0; j < 4; ++j) {
        int ee = we*64 + j*16 + lrow;
        float v = acc[i][j][r] + c_lds[(bb - bb0)*128 + ee];
        float ex = __expf(2.f*v);
        partial += (1.f - 2.f/(ex + 1.f)) * wd[e0 + ee];
      }
      partial += __shfl_xor(partial, 1);
      partial += __shfl_xor(partial, 2);
      partial += __shfl_xor(partial, 4);
      partial += __shfl_xor(partial, 8);
      ps[r] = partial;
    }
    if (lrow == 0) *(f32x4*)(spart + (size_t)p*25088 + mbase) = ps;
  }
}

// ---------------- finalize v2: softmax + MLP weighted sum (4 l-groups, uint4 loads) ----------------
__global__ __launch_bounds__(256) void finalize_kernel(const ushort_t* __restrict__ att_bf,
                                                       const float* __restrict__ spart,
                                                       float* __restrict__ out) {
  int b  = blockIdx.x >> 1;
  int dh = blockIdx.x & 1;
  int t  = threadIdx.x;
  __shared__ float wls[L_];
  __shared__ float red[8];
  __shared__ float pacc[4][8][64];   // [lgrp][j][dsub] — conflict-free scalar access

  float s = -1e30f;
  if (t < L_) {
    int m = b*L_ + t;
    float sum = 0.f;
    #pragma unroll
    for (int p = 0; p < 16; ++p) sum += spart[p*25088 + m];
    s = sum;                       // b_d2d omitted: softmax shift-invariant
  }
  float mx = s;
  #pragma unroll
  for (int off = 1; off < 64; off <<= 1) mx = fmaxf(mx, __shfl_xor(mx, off));
  if ((t & 63) == 0) red[t >> 6] = mx;
  __syncthreads();
  mx = fmaxf(fmaxf(red[0], red[1]), fmaxf(red[2], red[3]));
  float pr = (t < L_) ? __expf(s - mx) : 0.f;
  float ssum = pr;
  #pragma unroll
  for (int off = 1; off < 64; off <<= 1) ssum += __shfl_xor(ssum, off);
  if ((t & 63) == 0) red[4 + (t >> 6)] = ssum;
  __syncthreads();
  float tot = red[4] + red[5] + red[6] + red[7];
  if (t < L_) wls[t] = pr / tot;
  __syncthreads();

  // weighted sum: wave lg handles l in [lg*49, lg*49+49); lane dsub owns 8 d-columns.
  int dsub = t & 63, lg = t >> 6;
  const ushort_t* abase = att_bf + (size_t)b*L_*D_ + dh*512 + dsub*8
                        + (size_t)lg*49*D_;
  float a0=0.f,a1=0.f,a2=0.f,a3=0.f,a4=0.f,a5=0.f,a6=0.f,a7=0.f;
  #pragma unroll 7
  for (int li = 0; li < 49; ++li) {
    float wv = wls[lg*49 + li];
    uint4 v = *(const uint4*)(abase + (size_t)li*D_);
    a0 += wv*__uint_as_float(v.x << 16); a1 += wv*__uint_as_float(v.x & 0xffff0000u);
    a2 += wv*__uint_as_float(v.y << 16); a3 += wv*__uint_as_float(v.y & 0xffff0000u);
    a4 += wv*__uint_as_float(v.z << 16); a5 += wv*__uint_as_float(v.z & 0xffff0000u);
    a6 += wv*__uint_as_float(v.w << 16); a7 += wv*__uint_as_float(v.w & 0xffff0000u);
  }
  pacc[lg][0][dsub] = a0; pacc[lg][1][dsub] = a1;
  pacc[lg][2][dsub] = a2; pacc[lg][3][dsub] = a3;
  pacc[lg][4][dsub] = a4; pacc[lg][5][dsub] = a5;
  pacc[lg][6][dsub] = a6; pacc[lg][7][dsub] = a7;
  __syncthreads();
  if (t < 64) {
    float o[8];
    #pragma unroll
    for (int j = 0; j < 8; ++j)
      o[j] = pacc[0][j][t] + pacc[1][j][t] + pacc[2][j][t] + pacc[3][j][t];
    float* ob = out + (size_t)b*D_ + dh*512 + t*8;
    *(f32x4*)ob       = (f32x4){o[0], o[1], o[2], o[3]};
    *(f32x4*)(ob + 4) = (f32x4){o[4], o[5], o[6], o[7]};
  }
}

extern "C" void kernel_launch(void* const* d_in, const int* in_sizes, int n_in,
                              void* d_out, int out_size, void* d_ws, size_t ws_size,
                              hipStream_t stream) {
  (void)in_sizes; (void)n_in; (void)out_size; (void)ws_size;
  const float* x   = (const float*)d_in[0];
  const float* att = (const float*)d_in[1];
  const float* h   = (const float*)d_in[2];
  const float* Wa  = (const float*)d_in[3];
  const float* ba  = (const float*)d_in[4];
  const float* Wh  = (const float*)d_in[5];
  const float* bh  = (const float*)d_in[6];
  const float* Wi  = (const float*)d_in[7];
  const float* bi  = (const float*)d_in[8];
  const float* wd  = (const float*)d_in[9];
  // d_in[10] = b_d2d: softmax shift-invariant, unused

  char* ws = (char*)d_ws;
  ushort_t* att_bf = (ushort_t*)(ws + OFF_ATTBF);
  ushort_t* W_bf   = (ushort_t*)(ws + OFF_WBF);
  float*    spart  = (float*)(ws + OFF_SPART);
  float*    cpart  = (float*)(ws + OFF_CPART);
  float*    out    = (float*)d_out;

  hipLaunchKernelGGL(convert_kernel, dim3(2048), dim3(256), 0, stream,
                     att, Wa, att_bf, W_bf);
  hipLaunchKernelGGL(gemm_c_kernel, dim3(64), dim3(256), 0, stream,
                     x, h, Wi, Wh, cpart);
  hipLaunchKernelGGL(gemm_score_kernel, dim3(1568), dim3(256), 0, stream,
                     att_bf, W_bf, cpart, ba, bh, bi, wd, spart);
  hipLaunchKernelGGL(finalize_kernel, dim3(256), dim3(256), 0, stream,
                     att_bf, spart, out);
}